// Round 12
// baseline (1369.945 us; speedup 1.0000x reference)
//
#include <hip/hip_runtime.h>

#define S_LEN 256
#define BATCH 256

typedef _Float16 f16;
typedef _Float16 f16x8 __attribute__((ext_vector_type(8)));
typedef _Float16 f16x4 __attribute__((ext_vector_type(4)));
typedef float f32x4 __attribute__((ext_vector_type(4)));
typedef unsigned u32x4 __attribute__((ext_vector_type(4)));

__device__ inline float sigf(float x) { return 1.f / (1.f + __expf(-x)); }
__device__ inline float tanhf2(float x) { return 2.f * sigf(2.f * x) - 1.f; }

// LDS-only barrier: drain ds ops, leave global loads/stores in flight.
#define BARRIER_LGKM() asm volatile("s_waitcnt lgkmcnt(0)\n\ts_barrier" ::: "memory")

// ---------------- weight f32 -> f16 conversion ----------------
__global__ void k_convert(const float* __restrict__ w3, const float* __restrict__ w4,
                          const float* __restrict__ w6, const float* __restrict__ w7,
                          const float* __restrict__ w9, const float* __restrict__ w10,
                          const float* __restrict__ w12, const float* __restrict__ w13,
                          f16* __restrict__ dst) {
  int i = blockIdx.x * blockDim.x + threadIdx.x;
  const int n = 1310720;
  for (; i < n; i += gridDim.x * blockDim.x) {
    float v;
    if (i < 262144) {
      int m = i >> 16, j = i & 65535;
      v = (m == 0 ? w3 : m == 1 ? w4 : m == 2 ? w6 : w7)[j];
    } else {
      int k = i - 262144;
      int m = k >> 18, j = k & 262143;
      v = (m == 0 ? w9 : m == 1 ? w10 : m == 2 ? w12 : w13)[j];
    }
    dst[i] = (f16)v;
  }
}

__global__ void k_zero(unsigned* __restrict__ p, int n) {
  int i = blockIdx.x * blockDim.x + threadIdx.x;
  for (; i < n; i += gridDim.x * blockDim.x) p[i] = 0u;
}

// ---------------- embedding gather -> Xf [t][b][128] f16 ----------------
__global__ void k_gather(const int* __restrict__ insts, const float* __restrict__ emb,
                         f16* __restrict__ Xf) {
  int gid = blockIdx.x * blockDim.x + threadIdx.x;  // 0..2097151
  int row = gid >> 5;                               // t*B + b
  int ch = gid & 31;
  int t = row >> 8, b = row & 255;
  int v = insts[b * S_LEN + t];
  const float* src = emb + (size_t)v * 128 + ch * 4;
  f16x4 d;
  d[0] = (f16)src[0]; d[1] = (f16)src[1]; d[2] = (f16)src[2]; d[3] = (f16)src[3];
  *(f16x4*)&Xf[(size_t)row * 128 + ch * 4] = d;
}

// ---------------- char ih precompute: gih[dir][team][srel<64][512][16] ----------------
__global__ __launch_bounds__(256)
void k_gih_char(const f16* __restrict__ wbuf, const float* __restrict__ bias_f,
                const float* __restrict__ bias_b, const f16* __restrict__ Xf,
                f16* __restrict__ gih, int sbase) {
  const int team = blockIdx.x & 15;
  const int tc = (blockIdx.x >> 4) & 3;   // 4 chunks of 16 steps
  const int gc = (blockIdx.x >> 6) & 1;   // gate-row half
  const int dr = blockIdx.x >> 7;         // direction
  const int m0 = team * 16;
  const f16* Wih = wbuf + (dr ? 131072 : 0);
  const float* bias = dr ? bias_b : bias_f;
  const int lane = threadIdx.x & 63, wave = threadIdx.x >> 6;
  const int l15 = lane & 15, kb = (lane >> 4) * 8;
  const int rbase = gc * 256 + wave * 64;

  f16x8 fw[4][4];
  float bv[4];
#pragma unroll
  for (int tt = 0; tt < 4; ++tt) {
    int col = rbase + tt * 16 + l15;
    bv[tt] = bias[col];
#pragma unroll
    for (int ks = 0; ks < 4; ++ks)
      fw[tt][ks] = *(const f16x8*)&Wih[col * 128 + ks * 32 + kb];
  }

  for (int st = 0; st < 16; ++st) {
    const int srel = tc * 16 + st;
    const int s = sbase + srel;
    const int t_in = dr ? (255 - s) : s;
    f32x4 acc[4];
#pragma unroll
    for (int tt = 0; tt < 4; ++tt) { f32x4 a = {bv[tt], bv[tt], bv[tt], bv[tt]}; acc[tt] = a; }
    f16x8 ax[4];
#pragma unroll
    for (int ks = 0; ks < 4; ++ks)
      ax[ks] = *(const f16x8*)&Xf[(size_t)t_in * BATCH * 128 + (m0 + l15) * 128 + ks * 32 + kb];
#pragma unroll
    for (int ks = 0; ks < 4; ++ks)
#pragma unroll
      for (int tt = 0; tt < 4; ++tt)
        acc[tt] = __builtin_amdgcn_mfma_f32_16x16x32_f16(ax[ks], fw[tt][ks], acc[tt], 0, 0, 0);
#pragma unroll
    for (int tt = 0; tt < 4; ++tt) {
      f16x4 o;
#pragma unroll
      for (int r = 0; r < 4; ++r) o[r] = (f16)acc[tt][r];
      size_t off = ((((size_t)dr * 16 + team) * 64 + srel) * 512 + rbase + tt * 16 + l15) * 16 +
                   (lane >> 4) * 4;
      *(f16x4*)&gih[off] = o;
    }
  }
}

// ---------------- char hh chain: 32 blocks (dir x team), 512 thr ----------------
// In-lane gates; LDS-only barrier per step; 3-deep gnext prefetch pipeline so
// gih loads (often cross-XCD-dirty lines, ~1us) are hidden behind 3 steps.
__global__ __launch_bounds__(512)
void k_chain_char(const f16* __restrict__ wbuf, const f16* __restrict__ gih,
                  f16* __restrict__ chars, float* __restrict__ c_save, int sbase) {
  const int dr = blockIdx.x >> 4;
  const int teamc = blockIdx.x & 15;
  const f16* Whh = wbuf + (dr ? 196608 : 65536);
  const int tid = threadIdx.x, lane = tid & 63, wave = tid >> 6;
  const int l15 = lane & 15, kb = (lane >> 4) * 8;
  const int u0 = wave * 16;
  const int bq = lane >> 4;  // batch quad
  const int cbase = dr ? 128 : 0;

  __shared__ f16 hs[2][16][136];

  f16x8 fh[4][4];
#pragma unroll
  for (int g = 0; g < 4; ++g)
#pragma unroll
    for (int ks = 0; ks < 4; ++ks)
      fh[g][ks] = *(const f16x8*)&Whh[(g * 128 + u0 + l15) * 128 + ks * 32 + kb];

  float c[4];
  const size_t csoff = (((size_t)dr * 16 + teamc) * 128 + u0 + l15) * 16 + bq * 4;
  if (sbase) {
#pragma unroll
    for (int r = 0; r < 4; ++r) c[r] = c_save[csoff + r];
    const int t_prev = dr ? (256 - sbase) : (sbase - 1);
    int b = tid >> 5, u4 = (tid & 31) * 4;
    *(f16x4*)&hs[0][b][u4] =
        *(const f16x4*)&chars[((size_t)(teamc * 256 + t_prev) * 16 + b) * 256 + cbase + u4];
  } else {
#pragma unroll
    for (int r = 0; r < 4; ++r) c[r] = 0.f;
    int b = tid >> 5, u4 = (tid & 31) * 4;
    f16x4 z = {};
    *(f16x4*)&hs[0][b][u4] = z;
  }
  __syncthreads();

  const f16* gbase = gih + (((size_t)dr * 16 + teamc) * 64) * 512 * 16;
#define GLOAD(stq, g) \
  (*(const f16x4*)&gbase[((size_t)(stq) * 512 + (g) * 128 + u0 + l15) * 16 + bq * 4])
  // 3-deep prefetch pipeline (named sets, static indexing)
  f16x4 g0[4], g1[4], g2[4];
#pragma unroll
  for (int g = 0; g < 4; ++g) {
    g0[g] = GLOAD(0, g);
    g1[g] = GLOAD(1, g);
    g2[g] = GLOAD(2, g);
  }
  int par = 0;
  for (int st = 0; st < 64; ++st) {
    const int s = sbase + st;
    // issue prefetch for st+3 first (independent of this step's compute)
    f16x4 g3[4];
    const int stp = (st + 3 < 64) ? (st + 3) : 63;
#pragma unroll
    for (int g = 0; g < 4; ++g) g3[g] = GLOAD(stp, g);

    f16x8 ah[4];
#pragma unroll
    for (int ks = 0; ks < 4; ++ks) ah[ks] = *(const f16x8*)&hs[par][l15][ks * 32 + kb];
    f32x4 acc[4];
#pragma unroll
    for (int g = 0; g < 4; ++g) {
      f32x4 a = {(float)g0[g][0], (float)g0[g][1], (float)g0[g][2], (float)g0[g][3]};
      acc[g] = a;
    }
#pragma unroll
    for (int ks = 0; ks < 4; ++ks)
#pragma unroll
      for (int g = 0; g < 4; ++g)
        acc[g] = __builtin_amdgcn_mfma_f32_16x16x32_f16(ah[ks], fh[g][ks], acc[g], 0, 0, 0);
    const int t_out = dr ? (255 - s) : s;
#pragma unroll
    for (int r = 0; r < 4; ++r) {
      float cc = sigf(acc[1][r]) * c[r] + sigf(acc[0][r]) * tanhf2(acc[2][r]);
      c[r] = cc;
      f16 hv = (f16)(sigf(acc[3][r]) * tanhf2(cc));
      int b = bq * 4 + r;
      chars[((size_t)(teamc * 256 + t_out) * 16 + b) * 256 + cbase + u0 + l15] = hv;
      hs[par ^ 1][b][u0 + l15] = hv;
    }
    // rotate pipeline
#pragma unroll
    for (int g = 0; g < 4; ++g) { g0[g] = g1[g]; g1[g] = g2[g]; g2[g] = g3[g]; }
    par ^= 1;
    BARRIER_LGKM();
  }
#undef GLOAD
#pragma unroll
  for (int r = 0; r < 4; ++r) c_save[csoff + r] = c[r];
}

// ---------------- sub + word LSTM (R10 version verbatim: measured 866us) ----------
__global__ __launch_bounds__(256, 1)
void k_subword(const f16* __restrict__ wbuf, const f16* __restrict__ chars,
               const int* __restrict__ golds,
               const float* __restrict__ b_sub, const float* __restrict__ b_wrd,
               unsigned* __restrict__ pub, unsigned* __restrict__ flags,
               f16* __restrict__ H2) {
  const int team = blockIdx.x >> 4;
  const int q = blockIdx.x & 15;
  const int m0 = team * 16;
  const int h0 = q * 16;
  const int tid = threadIdx.x, lane = tid & 63, wave = tid >> 6;
  const int l15 = lane & 15, kb = (lane >> 4) * 8;

  const f16* sWih = wbuf + 262144;
  const f16* sWhh = wbuf + 524288;
  const f16* wWih = wbuf + 786432;
  const f16* wWhh = wbuf + 1048576;

  __shared__ f16 xs_s[16][264];
  __shared__ f16 h1_s[16][264];
  __shared__ f16 wh_s[16][264];
  __shared__ float gexS[16][68];
  __shared__ float gexW[16][68];
  __shared__ int golds_s[16][256];

  f32x4 fsi[8], fsh[8], fwi[8], fwh[8];
  const int wr = wave * 256 + h0 + l15;
#pragma unroll
  for (int ks = 0; ks < 8; ++ks) {
    fsi[ks] = *(const volatile f32x4*)&sWih[wr * 256 + ks * 32 + kb];
    fsh[ks] = *(const volatile f32x4*)&sWhh[wr * 256 + ks * 32 + kb];
    fwi[ks] = *(const volatile f32x4*)&wWih[wr * 256 + ks * 32 + kb];
    fwh[ks] = *(const volatile f32x4*)&wWhh[wr * 256 + ks * 32 + kb];
  }
  const float bS = b_sub[wr], bW = b_wrd[wr];

  for (int i = tid; i < 16 * 256; i += 256)
    golds_s[i >> 8][i & 255] = golds[(m0 + (i >> 8)) * S_LEN + (i & 255)];
  for (int i = tid; i < 16 * 264; i += 256) {
    ((f16*)xs_s)[i] = (f16)0.f;
    ((f16*)h1_s)[i] = (f16)0.f;
    ((f16*)wh_s)[i] = (f16)0.f;
  }
  const int cm = tid >> 4, cj = tid & 15;
  const int sr = tid >> 4;
  const int sc = (tid & 15) * 16;
  float c_sub = 0.f, c_wrd = 0.f, wh_reg = 0.f;
  __syncthreads();

  for (int i = 0; i <= S_LEN; ++i) {
    const bool doW = (i > 0), doS = (i < S_LEN);
    const int slotbase = ((i & 1) * 16 + team) << 12;

    f16x4 chpre[4];
    if (doS) {
#pragma unroll
      for (int p = 0; p < 4; ++p)
        chpre[p] = *(const f16x4*)&chars[(size_t)(((team * S_LEN + i) * 16 + sr) * 256) +
                                         sc + p * 4];
    }

    f32x4 accW = {bW, bW, bW, bW};
    f32x4 accS = {bS, bS, bS, bS};
    if (doW) {
#pragma unroll
      for (int ks = 0; ks < 8; ++ks) {
        f16x8 a1 = *(const f16x8*)&h1_s[l15][ks * 32 + kb];
        f16x8 aw = *(const f16x8*)&wh_s[l15][ks * 32 + kb];
        accW = __builtin_amdgcn_mfma_f32_16x16x32_f16(
            a1, __builtin_bit_cast(f16x8, fwi[ks]), accW, 0, 0, 0);
        accW = __builtin_amdgcn_mfma_f32_16x16x32_f16(
            aw, __builtin_bit_cast(f16x8, fwh[ks]), accW, 0, 0, 0);
      }
    }
    if (doS) {
      const bool keep = (i > 0) && (golds_s[l15][i > 0 ? i - 1 : 0] == 0);
      f16x8 z8 = {};
#pragma unroll
      for (int ks = 0; ks < 8; ++ks) {
        f16x8 axv = *(const f16x8*)&xs_s[l15][ks * 32 + kb];
        f16x8 a1 = *(const f16x8*)&h1_s[l15][ks * 32 + kb];
        a1 = keep ? a1 : z8;
        accS = __builtin_amdgcn_mfma_f32_16x16x32_f16(
            axv, __builtin_bit_cast(f16x8, fsi[ks]), accS, 0, 0, 0);
        accS = __builtin_amdgcn_mfma_f32_16x16x32_f16(
            a1, __builtin_bit_cast(f16x8, fsh[ks]), accS, 0, 0, 0);
      }
    }
#pragma unroll
    for (int r = 0; r < 4; ++r) {
      if (doW) gexW[(lane >> 4) * 4 + r][wave * 16 + l15] = accW[r];
      if (doS) gexS[(lane >> 4) * 4 + r][wave * 16 + l15] = accS[r];
    }
    __syncthreads();  // B1

    const int gprev = (i > 0) ? golds_s[cm][i - 1] : 1;
    if (doW) {
      float gi = gexW[cm][cj], gf = gexW[cm][16 + cj], gg = gexW[cm][32 + cj],
            go = gexW[cm][48 + cj];
      float c2 = sigf(gf) * c_wrd + sigf(gi) * tanhf2(gg);
      float h2 = sigf(go) * tanhf2(c2);
      bool adv = (gprev != 0);
      if (adv) { c_wrd = c2; wh_reg = h2; }
      H2[(size_t)(i - 1) * BATCH * 256 + (m0 + cm) * 256 + h0 + cj] = (f16)h2;
    }
    if (doS) {
      float gi = gexS[cm][cj], gf = gexS[cm][16 + cj], gg = gexS[cm][32 + cj],
            go = gexS[cm][48 + cj];
      float cp = (gprev == 0) ? c_sub : 0.f;
      float c1 = sigf(gf) * cp + sigf(gi) * tanhf2(gg);
      c_sub = c1;
      f16 h1 = (f16)(sigf(go) * tanhf2(c1));
      unsigned val = ((unsigned)__builtin_bit_cast(unsigned short, h1) << 16) |
                     (unsigned)__builtin_bit_cast(unsigned short, (f16)wh_reg);
      __hip_atomic_store(&pub[slotbase + cm * 256 + h0 + cj], val, __ATOMIC_RELAXED,
                         __HIP_MEMORY_SCOPE_AGENT);
    }
    __syncthreads();  // B2: publish stores drained (vmcnt 0 at barrier)

    if (doS) {
      if (tid == 0)
        __hip_atomic_store(&flags[(team * 16 + q) * 16], (unsigned)(i + 1), __ATOMIC_RELAXED,
                           __HIP_MEMORY_SCOPE_AGENT);
      if (tid < 64) {
        const unsigned tgt = (unsigned)(i + 1);
        while (true) {
          unsigned v = tgt;
          if (lane < 16)
            v = __hip_atomic_load(&flags[(team * 16 + lane) * 16], __ATOMIC_RELAXED,
                                  __HIP_MEMORY_SCOPE_AGENT);
          if (__all(v >= tgt)) break;
          __builtin_amdgcn_s_sleep(1);
        }
      }
      asm volatile("" ::: "memory");
      __syncthreads();  // B3
      // staging: 64B per thread via 4 wide coherent loads (sc0 sc1), single drain
      u32x4 w0, w1, w2, w3;
      {
        const unsigned* pb = &pub[slotbase + sr * 256 + sc];
        asm volatile(
            "global_load_dwordx4 %0, %4, off sc0 sc1\n\t"
            "global_load_dwordx4 %1, %5, off sc0 sc1\n\t"
            "global_load_dwordx4 %2, %6, off sc0 sc1\n\t"
            "global_load_dwordx4 %3, %7, off sc0 sc1\n\t"
            "s_waitcnt vmcnt(0)"
            : "=&v"(w0), "=&v"(w1), "=&v"(w2), "=&v"(w3)
            : "v"(pb), "v"(pb + 4), "v"(pb + 8), "v"(pb + 12));
      }
      union { unsigned short s[8]; f16x8 v; } uh0, uw0, uh1, uw1;
#pragma unroll
      for (int k = 0; k < 4; ++k) {
        uh0.s[k] = (unsigned short)(w0[k] >> 16);
        uw0.s[k] = (unsigned short)(w0[k] & 0xffffu);
        uh0.s[4 + k] = (unsigned short)(w1[k] >> 16);
        uw0.s[4 + k] = (unsigned short)(w1[k] & 0xffffu);
        uh1.s[k] = (unsigned short)(w2[k] >> 16);
        uw1.s[k] = (unsigned short)(w2[k] & 0xffffu);
        uh1.s[4 + k] = (unsigned short)(w3[k] >> 16);
        uw1.s[4 + k] = (unsigned short)(w3[k] & 0xffffu);
      }
      *(f16x8*)&h1_s[sr][sc] = uh0.v;
      *(f16x8*)&wh_s[sr][sc] = uw0.v;
      *(f16x8*)&h1_s[sr][sc + 8] = uh1.v;
      *(f16x8*)&wh_s[sr][sc + 8] = uw1.v;
#pragma unroll
      for (int p = 0; p < 4; ++p) *(f16x4*)&xs_s[sr][sc + p * 4] = chpre[p];
      __syncthreads();  // B4
    }
  }
}

// ---------------- classifier (unchanged) ----------------
__global__ __launch_bounds__(256)
void k_cls(const f16* __restrict__ H2, const f16* __restrict__ chars,
           const float* __restrict__ clsW, const float* __restrict__ clsb,
           float* __restrict__ out) {
  const int w = (blockIdx.x << 2) | (threadIdx.x >> 6);  // row = t*B + b
  const int lane = threadIdx.x & 63;
  const int t = w >> 8, b = w & 255;
  const f16* h2p = H2 + (size_t)w * 256;
  const f16* chp = chars + (size_t)(((b >> 4) * S_LEN + t) * 16 + (b & 15)) * 256;
  float s0 = 0.f, s1 = 0.f;
  f16x4 hv = *(const f16x4*)&h2p[lane * 4];
  f16x4 cv = *(const f16x4*)&chp[lane * 4];
#pragma unroll
  for (int qq = 0; qq < 4; ++qq) {
    int u = lane * 4 + qq;
    s0 += (float)hv[qq] * clsW[u] + (float)cv[qq] * clsW[256 + u];
    s1 += (float)hv[qq] * clsW[512 + u] + (float)cv[qq] * clsW[768 + u];
  }
#pragma unroll
  for (int off = 32; off >= 1; off >>= 1) {
    s0 += __shfl_down(s0, off);
    s1 += __shfl_down(s1, off);
  }
  if (lane == 0) {
    out[((size_t)b * S_LEN + t) * 2 + 0] = s0 + clsb[0];
    out[((size_t)b * S_LEN + t) * 2 + 1] = s1 + clsb[1];
  }
}

extern "C" void kernel_launch(void* const* d_in, const int* in_sizes, int n_in,
                              void* d_out, int out_size, void* d_ws, size_t ws_size,
                              hipStream_t stream) {
  const int* insts = (const int*)d_in[0];
  const int* golds = (const int*)d_in[1];
  const float* emb = (const float*)d_in[2];
  const float* wihf = (const float*)d_in[3];
  const float* whhf = (const float*)d_in[4];
  const float* bf = (const float*)d_in[5];
  const float* wihb = (const float*)d_in[6];
  const float* whhb = (const float*)d_in[7];
  const float* bb = (const float*)d_in[8];
  const float* swih = (const float*)d_in[9];
  const float* swhh = (const float*)d_in[10];
  const float* sb = (const float*)d_in[11];
  const float* wwih = (const float*)d_in[12];
  const float* wwhh = (const float*)d_in[13];
  const float* wb = (const float*)d_in[14];
  const float* clsW = (const float*)d_in[15];
  const float* clsb = (const float*)d_in[16];
  float* out = (float*)d_out;

  // workspace layout (bytes)
  const size_t OFF_W = 0;                     // 2,621,440 (weights f16)
  const size_t OFF_XF = 2621440;              // +16,777,216 (Xf; dead after gih #4)
  const size_t OFF_PUB = OFF_XF + 4194304;    // pub (subword phase, overlaid on Xf)
  const size_t OFF_FLAGS = OFF_PUB + 524288;  // flags 16,384
  const size_t OFF_CHARS = 19398656;          // +33,554,432 chars [teamc][t][16][256]
  const size_t OFF_A = 52953088;              // +33,554,432: gih (char phase) then H2
  const size_t OFF_TAIL = 86507520;           // c_save 262,144
  const size_t TOTAL = 87048192;
  if (ws_size < TOTAL) return;

  char* ws = (char*)d_ws;
  f16* wbuf = (f16*)(ws + OFF_W);
  f16* Xf = (f16*)(ws + OFF_XF);
  f16* chars = (f16*)(ws + OFF_CHARS);
  f16* gih = (f16*)(ws + OFF_A);
  f16* H2 = (f16*)(ws + OFF_A);
  float* c_save = (float*)(ws + OFF_TAIL);
  unsigned* pub = (unsigned*)(ws + OFF_PUB);
  unsigned* flags = (unsigned*)(ws + OFF_FLAGS);

  hipLaunchKernelGGL(k_convert, dim3(1024), dim3(256), 0, stream, wihf, whhf, wihb, whhb,
                     swih, swhh, wwih, wwhh, wbuf);
  hipLaunchKernelGGL(k_gather, dim3(8192), dim3(256), 0, stream, insts, emb, Xf);

  // char phase: 4 quarter-chunks of 64 steps, both directions concurrent
  for (int sb4 = 0; sb4 < 256; sb4 += 64) {
    hipLaunchKernelGGL(k_gih_char, dim3(256), dim3(256), 0, stream, wbuf, bf, bb, Xf, gih,
                       sb4);
    hipLaunchKernelGGL(k_chain_char, dim3(32), dim3(512), 0, stream, wbuf, gih, chars,
                       c_save, sb4);
  }

  // sub+word phase (R10 structure); flags live in dead Xf region
  hipLaunchKernelGGL(k_zero, dim3(16), dim3(256), 0, stream, (unsigned*)(ws + OFF_FLAGS),
                     4096);
  hipLaunchKernelGGL(k_subword, dim3(256), dim3(256), 0, stream, wbuf, chars, golds, sb, wb,
                     pub, flags, H2);
  hipLaunchKernelGGL(k_cls, dim3(16384), dim3(256), 0, stream, H2, chars, clsW, clsb, out);
}

// Round 13
// 1302.993 us; speedup vs baseline: 1.0514x; 1.0514x over previous
//
#include <hip/hip_runtime.h>

#define S_LEN 256
#define BATCH 256

typedef _Float16 f16;
typedef _Float16 f16x8 __attribute__((ext_vector_type(8)));
typedef _Float16 f16x4 __attribute__((ext_vector_type(4)));
typedef float f32x4 __attribute__((ext_vector_type(4)));
typedef unsigned u32x4 __attribute__((ext_vector_type(4)));

__device__ inline float sigf(float x) { return 1.f / (1.f + __expf(-x)); }
__device__ inline float tanhf2(float x) { return 2.f * sigf(2.f * x) - 1.f; }

// LDS-only barrier: drain ds ops, leave global loads/stores in flight.
#define BARRIER_LGKM() asm volatile("s_waitcnt lgkmcnt(0)\n\ts_barrier" ::: "memory")

// ---------------- weight f32 -> f16 conversion ----------------
__global__ void k_convert(const float* __restrict__ w3, const float* __restrict__ w4,
                          const float* __restrict__ w6, const float* __restrict__ w7,
                          const float* __restrict__ w9, const float* __restrict__ w10,
                          const float* __restrict__ w12, const float* __restrict__ w13,
                          f16* __restrict__ dst) {
  int i = blockIdx.x * blockDim.x + threadIdx.x;
  const int n = 1310720;
  for (; i < n; i += gridDim.x * blockDim.x) {
    float v;
    if (i < 262144) {
      int m = i >> 16, j = i & 65535;
      v = (m == 0 ? w3 : m == 1 ? w4 : m == 2 ? w6 : w7)[j];
    } else {
      int k = i - 262144;
      int m = k >> 18, j = k & 262143;
      v = (m == 0 ? w9 : m == 1 ? w10 : m == 2 ? w12 : w13)[j];
    }
    dst[i] = (f16)v;
  }
}

__global__ void k_zero(unsigned* __restrict__ p, int n) {
  int i = blockIdx.x * blockDim.x + threadIdx.x;
  for (; i < n; i += gridDim.x * blockDim.x) p[i] = 0u;
}

// ---------------- embedding gather -> Xf [t][b][128] f16 ----------------
__global__ void k_gather(const int* __restrict__ insts, const float* __restrict__ emb,
                         f16* __restrict__ Xf) {
  int gid = blockIdx.x * blockDim.x + threadIdx.x;  // 0..2097151
  int row = gid >> 5;                               // t*B + b
  int ch = gid & 31;
  int t = row >> 8, b = row & 255;
  int v = insts[b * S_LEN + t];
  const float* src = emb + (size_t)v * 128 + ch * 4;
  f16x4 d;
  d[0] = (f16)src[0]; d[1] = (f16)src[1]; d[2] = (f16)src[2]; d[3] = (f16)src[3];
  *(f16x4*)&Xf[(size_t)row * 128 + ch * 4] = d;
}

// ---------------- char BiLSTM, fused ih+hh chain ----------------
// 32 blocks (dir x team), 512 thr (8 waves; wave owns 16 units x 4 gates).
// Per step: hh-GEMM from LDS recurrence (critical path) + cell + in-register
// gate precompute for step t+1 from read-only Xf (overlaps). No gih tensor,
// no chunking. LDS-only barrier per step. ~215 VGPR at 2 waves/SIMD.
__global__ __launch_bounds__(512, 2)
void k_char_fused(const f16* __restrict__ wbuf, const float* __restrict__ bias_f,
                  const float* __restrict__ bias_b, const f16* __restrict__ Xf,
                  f16* __restrict__ chars) {
  const int dr = blockIdx.x >> 4;
  const int teamc = blockIdx.x & 15;
  const int m0 = teamc * 16;
  const f16* Wih = wbuf + (dr ? 131072 : 0);
  const f16* Whh = wbuf + (dr ? 196608 : 65536);
  const float* bias = dr ? bias_b : bias_f;
  const int tid = threadIdx.x, lane = tid & 63, wave = tid >> 6;
  const int l15 = lane & 15, kb = (lane >> 4) * 8;
  const int u0 = wave * 16;
  const int bq = lane >> 4;  // batch quad
  const int cbase = dr ? 128 : 0;

  __shared__ f16 hs[2][16][136];

  f16x8 fw[4][4], fh[4][4];
  float bv[4];
#pragma unroll
  for (int g = 0; g < 4; ++g) {
    const int row = g * 128 + u0 + l15;
    bv[g] = bias[row];
#pragma unroll
    for (int ks = 0; ks < 4; ++ks) {
      fw[g][ks] = *(const f16x8*)&Wih[row * 128 + ks * 32 + kb];
      fh[g][ks] = *(const f16x8*)&Whh[row * 128 + ks * 32 + kb];
    }
  }

  float c[4] = {0.f, 0.f, 0.f, 0.f};
  {
    int b = tid >> 5, u4 = (tid & 31) * 4;
    f16x4 z = {};
    *(f16x4*)&hs[0][b][u4] = z;
  }
  __syncthreads();

  // prologue: gate-precompute (ih part) for st=0
  f32x4 gacc[4];
  {
    const int t0 = dr ? 255 : 0;
    f16x8 ax[4];
#pragma unroll
    for (int ks = 0; ks < 4; ++ks)
      ax[ks] = *(const f16x8*)&Xf[(size_t)t0 * BATCH * 128 + (m0 + l15) * 128 + ks * 32 + kb];
#pragma unroll
    for (int g = 0; g < 4; ++g) { f32x4 a = {bv[g], bv[g], bv[g], bv[g]}; gacc[g] = a; }
#pragma unroll
    for (int ks = 0; ks < 4; ++ks)
#pragma unroll
      for (int g = 0; g < 4; ++g)
        gacc[g] = __builtin_amdgcn_mfma_f32_16x16x32_f16(ax[ks], fw[g][ks], gacc[g], 0, 0, 0);
  }

  int par = 0;
  for (int st = 0; st < 256; ++st) {
    // issue Xf loads for st+1 early (read-only, L2-clean)
    f16x8 axn[4];
    if (st < 255) {
      const int tn = dr ? (254 - st) : (st + 1);
#pragma unroll
      for (int ks = 0; ks < 4; ++ks)
        axn[ks] =
            *(const f16x8*)&Xf[(size_t)tn * BATCH * 128 + (m0 + l15) * 128 + ks * 32 + kb];
    }

    // hh recurrence (critical path)
    f16x8 ah[4];
#pragma unroll
    for (int ks = 0; ks < 4; ++ks) ah[ks] = *(const f16x8*)&hs[par][l15][ks * 32 + kb];
    f32x4 acc[4];
#pragma unroll
    for (int g = 0; g < 4; ++g) acc[g] = gacc[g];
#pragma unroll
    for (int ks = 0; ks < 4; ++ks)
#pragma unroll
      for (int g = 0; g < 4; ++g)
        acc[g] = __builtin_amdgcn_mfma_f32_16x16x32_f16(ah[ks], fh[g][ks], acc[g], 0, 0, 0);

    // in-lane cell: gates i,f,g,o of (batch bq*4+r, unit u0+l15) all local
    const int t_out = dr ? (255 - st) : st;
#pragma unroll
    for (int r = 0; r < 4; ++r) {
      float cc = sigf(acc[1][r]) * c[r] + sigf(acc[0][r]) * tanhf2(acc[2][r]);
      c[r] = cc;
      f16 hv = (f16)(sigf(acc[3][r]) * tanhf2(cc));
      int b = bq * 4 + r;
      chars[((size_t)(teamc * 256 + t_out) * 16 + b) * 256 + cbase + u0 + l15] = hv;
      hs[par ^ 1][b][u0 + l15] = hv;
    }

    // gate precompute for st+1 (independent of recurrence; overlaps)
    if (st < 255) {
#pragma unroll
      for (int g = 0; g < 4; ++g) { f32x4 a = {bv[g], bv[g], bv[g], bv[g]}; gacc[g] = a; }
#pragma unroll
      for (int ks = 0; ks < 4; ++ks)
#pragma unroll
        for (int g = 0; g < 4; ++g)
          gacc[g] =
              __builtin_amdgcn_mfma_f32_16x16x32_f16(axn[ks], fw[g][ks], gacc[g], 0, 0, 0);
    }
    par ^= 1;
    BARRIER_LGKM();  // LDS-only: recurrence ordered; chars stores stay in flight
  }
}

// ---------------- sub + word LSTM (R10 version verbatim: measured 866us) ----------
__global__ __launch_bounds__(256, 1)
void k_subword(const f16* __restrict__ wbuf, const f16* __restrict__ chars,
               const int* __restrict__ golds,
               const float* __restrict__ b_sub, const float* __restrict__ b_wrd,
               unsigned* __restrict__ pub, unsigned* __restrict__ flags,
               f16* __restrict__ H2) {
  const int team = blockIdx.x >> 4;
  const int q = blockIdx.x & 15;
  const int m0 = team * 16;
  const int h0 = q * 16;
  const int tid = threadIdx.x, lane = tid & 63, wave = tid >> 6;
  const int l15 = lane & 15, kb = (lane >> 4) * 8;

  const f16* sWih = wbuf + 262144;
  const f16* sWhh = wbuf + 524288;
  const f16* wWih = wbuf + 786432;
  const f16* wWhh = wbuf + 1048576;

  __shared__ f16 xs_s[16][264];
  __shared__ f16 h1_s[16][264];
  __shared__ f16 wh_s[16][264];
  __shared__ float gexS[16][68];
  __shared__ float gexW[16][68];
  __shared__ int golds_s[16][256];

  f32x4 fsi[8], fsh[8], fwi[8], fwh[8];
  const int wr = wave * 256 + h0 + l15;
#pragma unroll
  for (int ks = 0; ks < 8; ++ks) {
    fsi[ks] = *(const volatile f32x4*)&sWih[wr * 256 + ks * 32 + kb];
    fsh[ks] = *(const volatile f32x4*)&sWhh[wr * 256 + ks * 32 + kb];
    fwi[ks] = *(const volatile f32x4*)&wWih[wr * 256 + ks * 32 + kb];
    fwh[ks] = *(const volatile f32x4*)&wWhh[wr * 256 + ks * 32 + kb];
  }
  const float bS = b_sub[wr], bW = b_wrd[wr];

  for (int i = tid; i < 16 * 256; i += 256)
    golds_s[i >> 8][i & 255] = golds[(m0 + (i >> 8)) * S_LEN + (i & 255)];
  for (int i = tid; i < 16 * 264; i += 256) {
    ((f16*)xs_s)[i] = (f16)0.f;
    ((f16*)h1_s)[i] = (f16)0.f;
    ((f16*)wh_s)[i] = (f16)0.f;
  }
  const int cm = tid >> 4, cj = tid & 15;
  const int sr = tid >> 4;
  const int sc = (tid & 15) * 16;
  float c_sub = 0.f, c_wrd = 0.f, wh_reg = 0.f;
  __syncthreads();

  for (int i = 0; i <= S_LEN; ++i) {
    const bool doW = (i > 0), doS = (i < S_LEN);
    const int slotbase = ((i & 1) * 16 + team) << 12;

    f16x4 chpre[4];
    if (doS) {
#pragma unroll
      for (int p = 0; p < 4; ++p)
        chpre[p] = *(const f16x4*)&chars[(size_t)(((team * S_LEN + i) * 16 + sr) * 256) +
                                         sc + p * 4];
    }

    f32x4 accW = {bW, bW, bW, bW};
    f32x4 accS = {bS, bS, bS, bS};
    if (doW) {
#pragma unroll
      for (int ks = 0; ks < 8; ++ks) {
        f16x8 a1 = *(const f16x8*)&h1_s[l15][ks * 32 + kb];
        f16x8 aw = *(const f16x8*)&wh_s[l15][ks * 32 + kb];
        accW = __builtin_amdgcn_mfma_f32_16x16x32_f16(
            a1, __builtin_bit_cast(f16x8, fwi[ks]), accW, 0, 0, 0);
        accW = __builtin_amdgcn_mfma_f32_16x16x32_f16(
            aw, __builtin_bit_cast(f16x8, fwh[ks]), accW, 0, 0, 0);
      }
    }
    if (doS) {
      const bool keep = (i > 0) && (golds_s[l15][i > 0 ? i - 1 : 0] == 0);
      f16x8 z8 = {};
#pragma unroll
      for (int ks = 0; ks < 8; ++ks) {
        f16x8 axv = *(const f16x8*)&xs_s[l15][ks * 32 + kb];
        f16x8 a1 = *(const f16x8*)&h1_s[l15][ks * 32 + kb];
        a1 = keep ? a1 : z8;
        accS = __builtin_amdgcn_mfma_f32_16x16x32_f16(
            axv, __builtin_bit_cast(f16x8, fsi[ks]), accS, 0, 0, 0);
        accS = __builtin_amdgcn_mfma_f32_16x16x32_f16(
            a1, __builtin_bit_cast(f16x8, fsh[ks]), accS, 0, 0, 0);
      }
    }
#pragma unroll
    for (int r = 0; r < 4; ++r) {
      if (doW) gexW[(lane >> 4) * 4 + r][wave * 16 + l15] = accW[r];
      if (doS) gexS[(lane >> 4) * 4 + r][wave * 16 + l15] = accS[r];
    }
    __syncthreads();  // B1

    const int gprev = (i > 0) ? golds_s[cm][i - 1] : 1;
    if (doW) {
      float gi = gexW[cm][cj], gf = gexW[cm][16 + cj], gg = gexW[cm][32 + cj],
            go = gexW[cm][48 + cj];
      float c2 = sigf(gf) * c_wrd + sigf(gi) * tanhf2(gg);
      float h2 = sigf(go) * tanhf2(c2);
      bool adv = (gprev != 0);
      if (adv) { c_wrd = c2; wh_reg = h2; }
      H2[(size_t)(i - 1) * BATCH * 256 + (m0 + cm) * 256 + h0 + cj] = (f16)h2;
    }
    if (doS) {
      float gi = gexS[cm][cj], gf = gexS[cm][16 + cj], gg = gexS[cm][32 + cj],
            go = gexS[cm][48 + cj];
      float cp = (gprev == 0) ? c_sub : 0.f;
      float c1 = sigf(gf) * cp + sigf(gi) * tanhf2(gg);
      c_sub = c1;
      f16 h1 = (f16)(sigf(go) * tanhf2(c1));
      unsigned val = ((unsigned)__builtin_bit_cast(unsigned short, h1) << 16) |
                     (unsigned)__builtin_bit_cast(unsigned short, (f16)wh_reg);
      __hip_atomic_store(&pub[slotbase + cm * 256 + h0 + cj], val, __ATOMIC_RELAXED,
                         __HIP_MEMORY_SCOPE_AGENT);
    }
    __syncthreads();  // B2: publish stores drained (vmcnt 0 at barrier)

    if (doS) {
      if (tid == 0)
        __hip_atomic_store(&flags[(team * 16 + q) * 16], (unsigned)(i + 1), __ATOMIC_RELAXED,
                           __HIP_MEMORY_SCOPE_AGENT);
      if (tid < 64) {
        const unsigned tgt = (unsigned)(i + 1);
        while (true) {
          unsigned v = tgt;
          if (lane < 16)
            v = __hip_atomic_load(&flags[(team * 16 + lane) * 16], __ATOMIC_RELAXED,
                                  __HIP_MEMORY_SCOPE_AGENT);
          if (__all(v >= tgt)) break;
          __builtin_amdgcn_s_sleep(1);
        }
      }
      asm volatile("" ::: "memory");
      __syncthreads();  // B3
      // staging: 64B per thread via 4 wide coherent loads (sc0 sc1), single drain
      u32x4 w0, w1, w2, w3;
      {
        const unsigned* pb = &pub[slotbase + sr * 256 + sc];
        asm volatile(
            "global_load_dwordx4 %0, %4, off sc0 sc1\n\t"
            "global_load_dwordx4 %1, %5, off sc0 sc1\n\t"
            "global_load_dwordx4 %2, %6, off sc0 sc1\n\t"
            "global_load_dwordx4 %3, %7, off sc0 sc1\n\t"
            "s_waitcnt vmcnt(0)"
            : "=&v"(w0), "=&v"(w1), "=&v"(w2), "=&v"(w3)
            : "v"(pb), "v"(pb + 4), "v"(pb + 8), "v"(pb + 12));
      }
      union { unsigned short s[8]; f16x8 v; } uh0, uw0, uh1, uw1;
#pragma unroll
      for (int k = 0; k < 4; ++k) {
        uh0.s[k] = (unsigned short)(w0[k] >> 16);
        uw0.s[k] = (unsigned short)(w0[k] & 0xffffu);
        uh0.s[4 + k] = (unsigned short)(w1[k] >> 16);
        uw0.s[4 + k] = (unsigned short)(w1[k] & 0xffffu);
        uh1.s[k] = (unsigned short)(w2[k] >> 16);
        uw1.s[k] = (unsigned short)(w2[k] & 0xffffu);
        uh1.s[4 + k] = (unsigned short)(w3[k] >> 16);
        uw1.s[4 + k] = (unsigned short)(w3[k] & 0xffffu);
      }
      *(f16x8*)&h1_s[sr][sc] = uh0.v;
      *(f16x8*)&wh_s[sr][sc] = uw0.v;
      *(f16x8*)&h1_s[sr][sc + 8] = uh1.v;
      *(f16x8*)&wh_s[sr][sc + 8] = uw1.v;
#pragma unroll
      for (int p = 0; p < 4; ++p) *(f16x4*)&xs_s[sr][sc + p * 4] = chpre[p];
      __syncthreads();  // B4
    }
  }
}

// ---------------- classifier (unchanged) ----------------
__global__ __launch_bounds__(256)
void k_cls(const f16* __restrict__ H2, const f16* __restrict__ chars,
           const float* __restrict__ clsW, const float* __restrict__ clsb,
           float* __restrict__ out) {
  const int w = (blockIdx.x << 2) | (threadIdx.x >> 6);  // row = t*B + b
  const int lane = threadIdx.x & 63;
  const int t = w >> 8, b = w & 255;
  const f16* h2p = H2 + (size_t)w * 256;
  const f16* chp = chars + (size_t)(((b >> 4) * S_LEN + t) * 16 + (b & 15)) * 256;
  float s0 = 0.f, s1 = 0.f;
  f16x4 hv = *(const f16x4*)&h2p[lane * 4];
  f16x4 cv = *(const f16x4*)&chp[lane * 4];
#pragma unroll
  for (int qq = 0; qq < 4; ++qq) {
    int u = lane * 4 + qq;
    s0 += (float)hv[qq] * clsW[u] + (float)cv[qq] * clsW[256 + u];
    s1 += (float)hv[qq] * clsW[512 + u] + (float)cv[qq] * clsW[768 + u];
  }
#pragma unroll
  for (int off = 32; off >= 1; off >>= 1) {
    s0 += __shfl_down(s0, off);
    s1 += __shfl_down(s1, off);
  }
  if (lane == 0) {
    out[((size_t)b * S_LEN + t) * 2 + 0] = s0 + clsb[0];
    out[((size_t)b * S_LEN + t) * 2 + 1] = s1 + clsb[1];
  }
}

extern "C" void kernel_launch(void* const* d_in, const int* in_sizes, int n_in,
                              void* d_out, int out_size, void* d_ws, size_t ws_size,
                              hipStream_t stream) {
  const int* insts = (const int*)d_in[0];
  const int* golds = (const int*)d_in[1];
  const float* emb = (const float*)d_in[2];
  const float* wihf = (const float*)d_in[3];
  const float* whhf = (const float*)d_in[4];
  const float* bf = (const float*)d_in[5];
  const float* wihb = (const float*)d_in[6];
  const float* whhb = (const float*)d_in[7];
  const float* bb = (const float*)d_in[8];
  const float* swih = (const float*)d_in[9];
  const float* swhh = (const float*)d_in[10];
  const float* sb = (const float*)d_in[11];
  const float* wwih = (const float*)d_in[12];
  const float* wwhh = (const float*)d_in[13];
  const float* wb = (const float*)d_in[14];
  const float* clsW = (const float*)d_in[15];
  const float* clsb = (const float*)d_in[16];
  float* out = (float*)d_out;

  // workspace layout (bytes)
  const size_t OFF_W = 0;                     // 2,621,440 (weights f16)
  const size_t OFF_XF = 2621440;              // +16,777,216 (Xf; live through k_char_fused)
  const size_t OFF_PUB = OFF_XF + 4194304;    // pub (subword phase, overlaid on Xf)
  const size_t OFF_FLAGS = OFF_PUB + 524288;  // flags 16,384 (overlaid on Xf)
  const size_t OFF_CHARS = 19398656;          // +33,554,432 chars [teamc][t][16][256]
  const size_t OFF_A = 52953088;              // +33,554,432: H2
  const size_t TOTAL = 87048192;
  if (ws_size < TOTAL) return;

  char* ws = (char*)d_ws;
  f16* wbuf = (f16*)(ws + OFF_W);
  f16* Xf = (f16*)(ws + OFF_XF);
  f16* chars = (f16*)(ws + OFF_CHARS);
  f16* H2 = (f16*)(ws + OFF_A);
  unsigned* pub = (unsigned*)(ws + OFF_PUB);
  unsigned* flags = (unsigned*)(ws + OFF_FLAGS);

  hipLaunchKernelGGL(k_convert, dim3(1024), dim3(256), 0, stream, wihf, whhf, wihb, whhb,
                     swih, swhh, wwih, wwhh, wbuf);
  hipLaunchKernelGGL(k_gather, dim3(8192), dim3(256), 0, stream, insts, emb, Xf);

  // char phase: single fused launch (both directions, all 256 steps)
  hipLaunchKernelGGL(k_char_fused, dim3(32), dim3(512), 0, stream, wbuf, bf, bb, Xf, chars);

  // sub+word phase (R10 structure); flags live in Xf region (dead after char)
  hipLaunchKernelGGL(k_zero, dim3(16), dim3(256), 0, stream, (unsigned*)(ws + OFF_FLAGS),
                     4096);
  hipLaunchKernelGGL(k_subword, dim3(256), dim3(256), 0, stream, wbuf, chars, golds, sb, wb,
                     pub, flags, H2);
  hipLaunchKernelGGL(k_cls, dim3(16384), dim3(256), 0, stream, H2, chars, clsW, clsb, out);
}

// Round 14
// 1200.561 us; speedup vs baseline: 1.1411x; 1.0853x over previous
//
#include <hip/hip_runtime.h>

#define S_LEN 256
#define BATCH 256

typedef _Float16 f16;
typedef _Float16 f16x8 __attribute__((ext_vector_type(8)));
typedef _Float16 f16x4 __attribute__((ext_vector_type(4)));
typedef float f32x4 __attribute__((ext_vector_type(4)));
typedef unsigned u32x4 __attribute__((ext_vector_type(4)));

__device__ inline float sigf(float x) { return 1.f / (1.f + __expf(-x)); }
__device__ inline float tanhf2(float x) { return 2.f * sigf(2.f * x) - 1.f; }

// LDS-only barrier: drain ds ops, leave global loads/stores in flight.
#define BARRIER_LGKM() asm volatile("s_waitcnt lgkmcnt(0)\n\ts_barrier" ::: "memory")

// ---------------- weight f32 -> f16 conversion ----------------
__global__ void k_convert(const float* __restrict__ w3, const float* __restrict__ w4,
                          const float* __restrict__ w6, const float* __restrict__ w7,
                          const float* __restrict__ w9, const float* __restrict__ w10,
                          const float* __restrict__ w12, const float* __restrict__ w13,
                          f16* __restrict__ dst) {
  int i = blockIdx.x * blockDim.x + threadIdx.x;
  const int n = 1310720;
  for (; i < n; i += gridDim.x * blockDim.x) {
    float v;
    if (i < 262144) {
      int m = i >> 16, j = i & 65535;
      v = (m == 0 ? w3 : m == 1 ? w4 : m == 2 ? w6 : w7)[j];
    } else {
      int k = i - 262144;
      int m = k >> 18, j = k & 262143;
      v = (m == 0 ? w9 : m == 1 ? w10 : m == 2 ? w12 : w13)[j];
    }
    dst[i] = (f16)v;
  }
}

__global__ void k_zero(unsigned* __restrict__ p, int n) {
  int i = blockIdx.x * blockDim.x + threadIdx.x;
  for (; i < n; i += gridDim.x * blockDim.x) p[i] = 0u;
}

// ---------------- embedding gather -> Xf [t][b][128] f16 ----------------
__global__ void k_gather(const int* __restrict__ insts, const float* __restrict__ emb,
                         f16* __restrict__ Xf) {
  int gid = blockIdx.x * blockDim.x + threadIdx.x;  // 0..2097151
  int row = gid >> 5;                               // t*B + b
  int ch = gid & 31;
  int t = row >> 8, b = row & 255;
  int v = insts[b * S_LEN + t];
  const float* src = emb + (size_t)v * 128 + ch * 4;
  f16x4 d;
  d[0] = (f16)src[0]; d[1] = (f16)src[1]; d[2] = (f16)src[2]; d[3] = (f16)src[3];
  *(f16x4*)&Xf[(size_t)row * 128 + ch * 4] = d;
}

// ---------------- char BiLSTM, fused ih+hh chain, batch-split x4 ----------------
// 128 blocks (dir x 64 batch-slices of 4 rows), 512 thr (8 waves x 16 units).
// Batch rows are independent recurrences; only the unit dim is coupled (in-block).
// MFMA uses M=4 of 16 (garbage rows read zeros); cell redistributed via LDS gate
// exchange so ALL 512 threads do 1 cell each -> per-CU transcendental work /4.
__global__ __launch_bounds__(512, 2)
void k_char_fused(const f16* __restrict__ wbuf, const float* __restrict__ bias_f,
                  const float* __restrict__ bias_b, const f16* __restrict__ Xf,
                  f16* __restrict__ chars) {
  const int dr = blockIdx.x >> 6;
  const int slice = blockIdx.x & 63;   // batch rows slice*4 .. slice*4+3
  const int teamc = slice >> 2;
  const f16* Wih = wbuf + (dr ? 131072 : 0);
  const f16* Whh = wbuf + (dr ? 196608 : 65536);
  const float* bias = dr ? bias_b : bias_f;
  const int tid = threadIdx.x, lane = tid & 63, wave = tid >> 6;
  const int l15 = lane & 15, kb = (lane >> 4) * 8;
  const int bq = lane >> 4;
  const int u0 = wave * 16;
  const int cbase = dr ? 128 : 0;
  const int xrow = (slice * 4 + l15 < 256) ? (slice * 4 + l15) : 255;  // clamp garbage

  __shared__ f16 hs[2][16][136];     // rows 4..15 stay zero (garbage M-rows)
  __shared__ float gex[4][512];      // [batch][gate*128+unit]

  f16x8 fw[4][4], fh[4][4];
  float bv[4];
#pragma unroll
  for (int g = 0; g < 4; ++g) {
    const int row = g * 128 + u0 + l15;
    bv[g] = bias[row];
#pragma unroll
    for (int ks = 0; ks < 4; ++ks) {
      fw[g][ks] = *(const f16x8*)&Wih[row * 128 + ks * 32 + kb];
      fh[g][ks] = *(const f16x8*)&Whh[row * 128 + ks * 32 + kb];
    }
  }

  for (int i = tid; i < 2 * 16 * 136; i += 512) ((f16*)hs)[i] = (f16)0.f;
  __syncthreads();

  // cell thread mapping: 1 cell per thread
  const int cb = tid >> 7;        // batch 0..3
  const int cu = tid & 127;       // unit 0..127
  float c = 0.f;

  // prologue: ih gates for st=0
  f32x4 gacc[4];
  {
    const int t0 = dr ? 255 : 0;
    f16x8 ax[4];
#pragma unroll
    for (int ks = 0; ks < 4; ++ks)
      ax[ks] = *(const f16x8*)&Xf[(size_t)t0 * BATCH * 128 + xrow * 128 + ks * 32 + kb];
#pragma unroll
    for (int g = 0; g < 4; ++g) { f32x4 a = {bv[g], bv[g], bv[g], bv[g]}; gacc[g] = a; }
#pragma unroll
    for (int ks = 0; ks < 4; ++ks)
#pragma unroll
      for (int g = 0; g < 4; ++g)
        gacc[g] = __builtin_amdgcn_mfma_f32_16x16x32_f16(ax[ks], fw[g][ks], gacc[g], 0, 0, 0);
  }

  int par = 0;
  for (int st = 0; st < 256; ++st) {
    // issue Xf loads for st+1 early (read-only)
    f16x8 axn[4];
    if (st < 255) {
      const int tn = dr ? (254 - st) : (st + 1);
#pragma unroll
      for (int ks = 0; ks < 4; ++ks)
        axn[ks] = *(const f16x8*)&Xf[(size_t)tn * BATCH * 128 + xrow * 128 + ks * 32 + kb];
    }

    // hh recurrence on top of precomputed ih gates
    f16x8 ah[4];
#pragma unroll
    for (int ks = 0; ks < 4; ++ks) ah[ks] = *(const f16x8*)&hs[par][l15][ks * 32 + kb];
    f32x4 acc[4];
#pragma unroll
    for (int g = 0; g < 4; ++g) acc[g] = gacc[g];
#pragma unroll
    for (int ks = 0; ks < 4; ++ks)
#pragma unroll
      for (int g = 0; g < 4; ++g)
        acc[g] = __builtin_amdgcn_mfma_f32_16x16x32_f16(ah[ks], fh[g][ks], acc[g], 0, 0, 0);

    // gate exchange: valid lanes (bq==0) hold batch r=0..3 at unit u0+l15
    if (bq == 0) {
#pragma unroll
      for (int g = 0; g < 4; ++g)
#pragma unroll
        for (int r = 0; r < 4; ++r) gex[r][g * 128 + u0 + l15] = acc[g][r];
    }
    BARRIER_LGKM();  // B1: gates visible

    // cell: 1 per thread, all 512 threads active (trans spread over whole CU)
    {
      float gi = gex[cb][cu], gf = gex[cb][128 + cu], gg = gex[cb][256 + cu],
            go = gex[cb][384 + cu];
      float cc = sigf(gf) * c + sigf(gi) * tanhf2(gg);
      c = cc;
      f16 hv = (f16)(sigf(go) * tanhf2(cc));
      const int t_out = dr ? (255 - st) : st;
      const int gr = slice * 4 + cb;  // global batch row
      chars[((size_t)(teamc * 256 + t_out) * 16 + (gr & 15)) * 256 + cbase + cu] = hv;
      hs[par ^ 1][cb][cu] = hv;
    }

    // ih gates for st+1 (independent; overlaps on MFMA pipe)
    if (st < 255) {
#pragma unroll
      for (int g = 0; g < 4; ++g) { f32x4 a = {bv[g], bv[g], bv[g], bv[g]}; gacc[g] = a; }
#pragma unroll
      for (int ks = 0; ks < 4; ++ks)
#pragma unroll
        for (int g = 0; g < 4; ++g)
          gacc[g] =
              __builtin_amdgcn_mfma_f32_16x16x32_f16(axn[ks], fw[g][ks], gacc[g], 0, 0, 0);
    }
    par ^= 1;
    BARRIER_LGKM();  // B2: h staged for next step; chars stores stay in flight
  }
}

// ---------------- sub + word LSTM (R10 version verbatim: measured ~850us) ----------
__global__ __launch_bounds__(256, 1)
void k_subword(const f16* __restrict__ wbuf, const f16* __restrict__ chars,
               const int* __restrict__ golds,
               const float* __restrict__ b_sub, const float* __restrict__ b_wrd,
               unsigned* __restrict__ pub, unsigned* __restrict__ flags,
               f16* __restrict__ H2) {
  const int team = blockIdx.x >> 4;
  const int q = blockIdx.x & 15;
  const int m0 = team * 16;
  const int h0 = q * 16;
  const int tid = threadIdx.x, lane = tid & 63, wave = tid >> 6;
  const int l15 = lane & 15, kb = (lane >> 4) * 8;

  const f16* sWih = wbuf + 262144;
  const f16* sWhh = wbuf + 524288;
  const f16* wWih = wbuf + 786432;
  const f16* wWhh = wbuf + 1048576;

  __shared__ f16 xs_s[16][264];
  __shared__ f16 h1_s[16][264];
  __shared__ f16 wh_s[16][264];
  __shared__ float gexS[16][68];
  __shared__ float gexW[16][68];
  __shared__ int golds_s[16][256];

  f32x4 fsi[8], fsh[8], fwi[8], fwh[8];
  const int wr = wave * 256 + h0 + l15;
#pragma unroll
  for (int ks = 0; ks < 8; ++ks) {
    fsi[ks] = *(const volatile f32x4*)&sWih[wr * 256 + ks * 32 + kb];
    fsh[ks] = *(const volatile f32x4*)&sWhh[wr * 256 + ks * 32 + kb];
    fwi[ks] = *(const volatile f32x4*)&wWih[wr * 256 + ks * 32 + kb];
    fwh[ks] = *(const volatile f32x4*)&wWhh[wr * 256 + ks * 32 + kb];
  }
  const float bS = b_sub[wr], bW = b_wrd[wr];

  for (int i = tid; i < 16 * 256; i += 256)
    golds_s[i >> 8][i & 255] = golds[(m0 + (i >> 8)) * S_LEN + (i & 255)];
  for (int i = tid; i < 16 * 264; i += 256) {
    ((f16*)xs_s)[i] = (f16)0.f;
    ((f16*)h1_s)[i] = (f16)0.f;
    ((f16*)wh_s)[i] = (f16)0.f;
  }
  const int cm = tid >> 4, cj = tid & 15;
  const int sr = tid >> 4;
  const int sc = (tid & 15) * 16;
  float c_sub = 0.f, c_wrd = 0.f, wh_reg = 0.f;
  __syncthreads();

  for (int i = 0; i <= S_LEN; ++i) {
    const bool doW = (i > 0), doS = (i < S_LEN);
    const int slotbase = ((i & 1) * 16 + team) << 12;

    f16x4 chpre[4];
    if (doS) {
#pragma unroll
      for (int p = 0; p < 4; ++p)
        chpre[p] = *(const f16x4*)&chars[(size_t)(((team * S_LEN + i) * 16 + sr) * 256) +
                                         sc + p * 4];
    }

    f32x4 accW = {bW, bW, bW, bW};
    f32x4 accS = {bS, bS, bS, bS};
    if (doW) {
#pragma unroll
      for (int ks = 0; ks < 8; ++ks) {
        f16x8 a1 = *(const f16x8*)&h1_s[l15][ks * 32 + kb];
        f16x8 aw = *(const f16x8*)&wh_s[l15][ks * 32 + kb];
        accW = __builtin_amdgcn_mfma_f32_16x16x32_f16(
            a1, __builtin_bit_cast(f16x8, fwi[ks]), accW, 0, 0, 0);
        accW = __builtin_amdgcn_mfma_f32_16x16x32_f16(
            aw, __builtin_bit_cast(f16x8, fwh[ks]), accW, 0, 0, 0);
      }
    }
    if (doS) {
      const bool keep = (i > 0) && (golds_s[l15][i > 0 ? i - 1 : 0] == 0);
      f16x8 z8 = {};
#pragma unroll
      for (int ks = 0; ks < 8; ++ks) {
        f16x8 axv = *(const f16x8*)&xs_s[l15][ks * 32 + kb];
        f16x8 a1 = *(const f16x8*)&h1_s[l15][ks * 32 + kb];
        a1 = keep ? a1 : z8;
        accS = __builtin_amdgcn_mfma_f32_16x16x32_f16(
            axv, __builtin_bit_cast(f16x8, fsi[ks]), accS, 0, 0, 0);
        accS = __builtin_amdgcn_mfma_f32_16x16x32_f16(
            a1, __builtin_bit_cast(f16x8, fsh[ks]), accS, 0, 0, 0);
      }
    }
#pragma unroll
    for (int r = 0; r < 4; ++r) {
      if (doW) gexW[(lane >> 4) * 4 + r][wave * 16 + l15] = accW[r];
      if (doS) gexS[(lane >> 4) * 4 + r][wave * 16 + l15] = accS[r];
    }
    __syncthreads();  // B1

    const int gprev = (i > 0) ? golds_s[cm][i - 1] : 1;
    if (doW) {
      float gi = gexW[cm][cj], gf = gexW[cm][16 + cj], gg = gexW[cm][32 + cj],
            go = gexW[cm][48 + cj];
      float c2 = sigf(gf) * c_wrd + sigf(gi) * tanhf2(gg);
      float h2 = sigf(go) * tanhf2(c2);
      bool adv = (gprev != 0);
      if (adv) { c_wrd = c2; wh_reg = h2; }
      H2[(size_t)(i - 1) * BATCH * 256 + (m0 + cm) * 256 + h0 + cj] = (f16)h2;
    }
    if (doS) {
      float gi = gexS[cm][cj], gf = gexS[cm][16 + cj], gg = gexS[cm][32 + cj],
            go = gexS[cm][48 + cj];
      float cp = (gprev == 0) ? c_sub : 0.f;
      float c1 = sigf(gf) * cp + sigf(gi) * tanhf2(gg);
      c_sub = c1;
      f16 h1 = (f16)(sigf(go) * tanhf2(c1));
      unsigned val = ((unsigned)__builtin_bit_cast(unsigned short, h1) << 16) |
                     (unsigned)__builtin_bit_cast(unsigned short, (f16)wh_reg);
      __hip_atomic_store(&pub[slotbase + cm * 256 + h0 + cj], val, __ATOMIC_RELAXED,
                         __HIP_MEMORY_SCOPE_AGENT);
    }
    __syncthreads();  // B2: publish stores drained (vmcnt 0 at barrier)

    if (doS) {
      if (tid == 0)
        __hip_atomic_store(&flags[(team * 16 + q) * 16], (unsigned)(i + 1), __ATOMIC_RELAXED,
                           __HIP_MEMORY_SCOPE_AGENT);
      if (tid < 64) {
        const unsigned tgt = (unsigned)(i + 1);
        while (true) {
          unsigned v = tgt;
          if (lane < 16)
            v = __hip_atomic_load(&flags[(team * 16 + lane) * 16], __ATOMIC_RELAXED,
                                  __HIP_MEMORY_SCOPE_AGENT);
          if (__all(v >= tgt)) break;
          __builtin_amdgcn_s_sleep(1);
        }
      }
      asm volatile("" ::: "memory");
      __syncthreads();  // B3
      // staging: 64B per thread via 4 wide coherent loads (sc0 sc1), single drain
      u32x4 w0, w1, w2, w3;
      {
        const unsigned* pb = &pub[slotbase + sr * 256 + sc];
        asm volatile(
            "global_load_dwordx4 %0, %4, off sc0 sc1\n\t"
            "global_load_dwordx4 %1, %5, off sc0 sc1\n\t"
            "global_load_dwordx4 %2, %6, off sc0 sc1\n\t"
            "global_load_dwordx4 %3, %7, off sc0 sc1\n\t"
            "s_waitcnt vmcnt(0)"
            : "=&v"(w0), "=&v"(w1), "=&v"(w2), "=&v"(w3)
            : "v"(pb), "v"(pb + 4), "v"(pb + 8), "v"(pb + 12));
      }
      union { unsigned short s[8]; f16x8 v; } uh0, uw0, uh1, uw1;
#pragma unroll
      for (int k = 0; k < 4; ++k) {
        uh0.s[k] = (unsigned short)(w0[k] >> 16);
        uw0.s[k] = (unsigned short)(w0[k] & 0xffffu);
        uh0.s[4 + k] = (unsigned short)(w1[k] >> 16);
        uw0.s[4 + k] = (unsigned short)(w1[k] & 0xffffu);
        uh1.s[k] = (unsigned short)(w2[k] >> 16);
        uw1.s[k] = (unsigned short)(w2[k] & 0xffffu);
        uh1.s[4 + k] = (unsigned short)(w3[k] >> 16);
        uw1.s[4 + k] = (unsigned short)(w3[k] & 0xffffu);
      }
      *(f16x8*)&h1_s[sr][sc] = uh0.v;
      *(f16x8*)&wh_s[sr][sc] = uw0.v;
      *(f16x8*)&h1_s[sr][sc + 8] = uh1.v;
      *(f16x8*)&wh_s[sr][sc + 8] = uw1.v;
#pragma unroll
      for (int p = 0; p < 4; ++p) *(f16x4*)&xs_s[sr][sc + p * 4] = chpre[p];
      __syncthreads();  // B4
    }
  }
}

// ---------------- classifier (unchanged) ----------------
__global__ __launch_bounds__(256)
void k_cls(const f16* __restrict__ H2, const f16* __restrict__ chars,
           const float* __restrict__ clsW, const float* __restrict__ clsb,
           float* __restrict__ out) {
  const int w = (blockIdx.x << 2) | (threadIdx.x >> 6);  // row = t*B + b
  const int lane = threadIdx.x & 63;
  const int t = w >> 8, b = w & 255;
  const f16* h2p = H2 + (size_t)w * 256;
  const f16* chp = chars + (size_t)(((b >> 4) * S_LEN + t) * 16 + (b & 15)) * 256;
  float s0 = 0.f, s1 = 0.f;
  f16x4 hv = *(const f16x4*)&h2p[lane * 4];
  f16x4 cv = *(const f16x4*)&chp[lane * 4];
#pragma unroll
  for (int qq = 0; qq < 4; ++qq) {
    int u = lane * 4 + qq;
    s0 += (float)hv[qq] * clsW[u] + (float)cv[qq] * clsW[256 + u];
    s1 += (float)hv[qq] * clsW[512 + u] + (float)cv[qq] * clsW[768 + u];
  }
#pragma unroll
  for (int off = 32; off >= 1; off >>= 1) {
    s0 += __shfl_down(s0, off);
    s1 += __shfl_down(s1, off);
  }
  if (lane == 0) {
    out[((size_t)b * S_LEN + t) * 2 + 0] = s0 + clsb[0];
    out[((size_t)b * S_LEN + t) * 2 + 1] = s1 + clsb[1];
  }
}

extern "C" void kernel_launch(void* const* d_in, const int* in_sizes, int n_in,
                              void* d_out, int out_size, void* d_ws, size_t ws_size,
                              hipStream_t stream) {
  const int* insts = (const int*)d_in[0];
  const int* golds = (const int*)d_in[1];
  const float* emb = (const float*)d_in[2];
  const float* wihf = (const float*)d_in[3];
  const float* whhf = (const float*)d_in[4];
  const float* bf = (const float*)d_in[5];
  const float* wihb = (const float*)d_in[6];
  const float* whhb = (const float*)d_in[7];
  const float* bb = (const float*)d_in[8];
  const float* swih = (const float*)d_in[9];
  const float* swhh = (const float*)d_in[10];
  const float* sb = (const float*)d_in[11];
  const float* wwih = (const float*)d_in[12];
  const float* wwhh = (const float*)d_in[13];
  const float* wb = (const float*)d_in[14];
  const float* clsW = (const float*)d_in[15];
  const float* clsb = (const float*)d_in[16];
  float* out = (float*)d_out;

  // workspace layout (bytes)
  const size_t OFF_W = 0;                     // 2,621,440 (weights f16)
  const size_t OFF_XF = 2621440;              // +16,777,216 (Xf; live through k_char_fused)
  const size_t OFF_PUB = OFF_XF + 4194304;    // pub (subword phase, overlaid on Xf)
  const size_t OFF_FLAGS = OFF_PUB + 524288;  // flags 16,384 (overlaid on Xf)
  const size_t OFF_CHARS = 19398656;          // +33,554,432 chars [teamc][t][16][256]
  const size_t OFF_A = 52953088;              // +33,554,432: H2
  const size_t TOTAL = 87048192;
  if (ws_size < TOTAL) return;

  char* ws = (char*)d_ws;
  f16* wbuf = (f16*)(ws + OFF_W);
  f16* Xf = (f16*)(ws + OFF_XF);
  f16* chars = (f16*)(ws + OFF_CHARS);
  f16* H2 = (f16*)(ws + OFF_A);
  unsigned* pub = (unsigned*)(ws + OFF_PUB);
  unsigned* flags = (unsigned*)(ws + OFF_FLAGS);

  hipLaunchKernelGGL(k_convert, dim3(1024), dim3(256), 0, stream, wihf, whhf, wihb, whhb,
                     swih, swhh, wwih, wwhh, wbuf);
  hipLaunchKernelGGL(k_gather, dim3(8192), dim3(256), 0, stream, insts, emb, Xf);

  // char phase: single fused launch, 128 blocks (batch-split x4)
  hipLaunchKernelGGL(k_char_fused, dim3(128), dim3(512), 0, stream, wbuf, bf, bb, Xf, chars);

  // sub+word phase (R10 structure); flags live in Xf region (dead after char)
  hipLaunchKernelGGL(k_zero, dim3(16), dim3(256), 0, stream, (unsigned*)(ws + OFF_FLAGS),
                     4096);
  hipLaunchKernelGGL(k_subword, dim3(256), dim3(256), 0, stream, wbuf, chars, golds, sb, wb,
                     pub, flags, H2);
  hipLaunchKernelGGL(k_cls, dim3(16384), dim3(256), 0, stream, H2, chars, clsW, clsb, out);
}